// Round 11
// baseline (358.438 us; speedup 1.0000x reference)
//
#include <hip/hip_runtime.h>
#include <hip/hip_bf16.h>

#define TWO_N  8192
#define N_HALF 4096
#define DIMS   256

typedef __bf16 bf16x8 __attribute__((ext_vector_type(8)));
typedef float  f32x16 __attribute__((ext_vector_type(16)));
typedef unsigned short ushort8v __attribute__((ext_vector_type(8)));

// raw v_exp_f32 (args here are bounded |x| <= ~3, no denormal/range handling needed)
__device__ __forceinline__ float fast_exp2(float x) {
#if __has_builtin(__builtin_amdgcn_exp2f)
    return __builtin_amdgcn_exp2f(x);
#else
    float r; asm("v_exp_f32 %0, %1" : "=v"(r) : "v"(x)); return r;
#endif
}

// async global->LDS, 16B per lane: LDS dest = wave-uniform base (HW adds
// lane*16), global src = per-lane pointer (guide §5; m97 pattern).
#define GLOAD_LDS16(g, l)                                                      \
    __builtin_amdgcn_global_load_lds(                                          \
        (const __attribute__((address_space(1))) unsigned int*)(g),            \
        (__attribute__((address_space(3))) unsigned int*)(l), 16, 0, 0)

// ---------------------------------------------------------------------------
// Kernel 1: normalize rows of reps = cat([zjs, zis]), pre-scale by
// sqrt(2*log2(e)) so MFMA dot = (1/TEMP)*log2(e)*sim, and store in
// 32x32x16-MFMA fragment order: chunk = (row/32)*16 + kk  (kk = K/16 step),
// within chunk lane L = khalf*32 + (row%32) holds 8 bf16 of
// k = kk*16 + khalf*8 + j.  One 32-lane half-wave per row.
// ---------------------------------------------------------------------------
__global__ __launch_bounds__(256) void nrm_kernel(const float* __restrict__ zis,
                                                  const float* __restrict__ zjs,
                                                  unsigned short* __restrict__ swz)
{
    const int tid = threadIdx.x;
    const int l32 = tid & 31;
    const int row = blockIdx.x * 8 + (tid >> 5);
    const int k0  = l32 * 8;

    const float* src = (row < N_HALF) ? (zjs + (size_t)row * DIMS)
                                      : (zis + (size_t)(row - N_HALF) * DIMS);
    const float4 v0 = reinterpret_cast<const float4*>(src + k0)[0];
    const float4 v1 = reinterpret_cast<const float4*>(src + k0 + 4)[0];
    float ss = v0.x * v0.x + v0.y * v0.y + v0.z * v0.z + v0.w * v0.w
             + v1.x * v1.x + v1.y * v1.y + v1.z * v1.z + v1.w * v1.w;
#pragma unroll
    for (int m = 1; m < 32; m <<= 1) ss += __shfl_xor(ss, m, 64);
    // norms ~16 for N(0,1) rows; cosine eps path can never trigger
    const float inv = rsqrtf(ss) * 1.69864360045f;  // * sqrt(2*log2(e))

    const float vals[8] = {v0.x, v0.y, v0.z, v0.w, v1.x, v1.y, v1.z, v1.w};
    ushort8v o;
#pragma unroll
    for (int j = 0; j < 8; ++j) {
        __hip_bfloat16 b = __float2bfloat16(vals[j] * inv);
        o[j] = *reinterpret_cast<unsigned short*>(&b);
    }
    // kk = k0>>4 = l32>>1, khalf = l32&1
    const size_t addr = ((size_t)((row >> 5) * 16 + (l32 >> 1)) * 64
                         + (l32 & 1) * 32 + (row & 31)) * 8;
    *reinterpret_cast<ushort8v*>(swz + addr) = o;
}

// ---------------------------------------------------------------------------
// Kernel 2 (R7 structure, 32x32x16 MFMA): fused scaled-Gram + exp2 row
// partial sums + diag mask + positive extraction.
// 512x512 tile, 1 block/CU (grid 256), 8 waves x 64 rows (2 x 32-row groups),
// chunked LDS A (4 x 64KB dbuf), one vmcnt(0)+barrier per 128-col chunk.
// MFMA shape 16x16x32 -> 32x32x16 (~15% faster pipe, half the instructions).
// Operand-role mapping (verified convention from R0's 16x16 kernel):
// with mfma(A=col-frag, B=row-frag), D's lane&31 index = B-operand = SIM ROW,
// reg-map (reg&3)+8*(reg>>2)+4*(lane>>5) = A-operand = SIM COL. So every
// lane's 16 C-regs belong to ONE row (wr0 + t*32 + (lane&31)) at 16 col
// offsets -> per-row sums are lane-local; epilogue = sum 16 regs + one
// shfl_xor(32) (halves cover complementary col-offset sets) + one store.
// Diag/positive triggers: within the diag sub-block (c0 == wr0+t*32 resp.
// (wr0+t*32)^4096) the condition collapses to rr == cl31 either way.
// ---------------------------------------------------------------------------
__global__ __launch_bounds__(512, 2) void ntx_kernel(const __bf16* __restrict__ swz,
                                                     float* __restrict__ rowsum_part,
                                                     float* __restrict__ pos_part)
{
    __shared__ __bf16 abuf[2][32768];   // 2 x 64 KB (chunk double-buffer)

    const int lane = threadIdx.x & 63;
    const int wave = threadIdx.x >> 6;   // 0..7
    const int half = lane >> 5;          // k-half of A/B frags, col-offset group of C
    const int cl31 = lane & 31;          // C/D row within the 32-row group

    const int rg   = blockIdx.x & 15;    // 16 row groups of 512
    const int cs   = blockIdx.x >> 4;    // 16 col groups of 512
    const int wr0  = rg * 512 + wave * 64;
    const int p0   = wr0 ^ N_HALF;       // partner-row window (positives)
    const int g0   = wr0 >> 5;           // first 32-row fragment group

    // stage chunk c (128 cols = 4 col-32-groups x 16 K-chunks = 64 x 1KB):
    // wave w covers sub-chunks [w*8, w*8+8).
    auto stage = [&](int buf, int c) {
        const __bf16* gsrc = swz + ((size_t)(cs * 256 + c * 64 + wave * 8)) * 512 + lane * 8;
#pragma unroll
        for (int h = 0; h < 8; ++h)
            GLOAD_LDS16(gsrc + h * 512, &abuf[buf][(wave * 8 + h) * 512]);
    };

    stage(0, 0);   // chunk 0 in flight while B fragments load

    // Hoist B (row) fragments: 2 groups of 32 rows, 16 K-chunks each (128 VGPR).
    bf16x8 bfrag[2][16];
#pragma unroll
    for (int t = 0; t < 2; ++t)
#pragma unroll
        for (int ks = 0; ks < 16; ++ks)
            bfrag[t][ks] = *reinterpret_cast<const bf16x8*>(
                swz + (size_t)((g0 + t) * 16 + ks) * 512 + lane * 8);

    float sums0[16], sums1[16];
#pragma unroll
    for (int g = 0; g < 16; ++g) { sums0[g] = 0.f; sums1[g] = 0.f; }
    float pos_acc = 0.f;

    asm volatile("s_waitcnt vmcnt(0)" ::: "memory");
    __syncthreads();   // chunk 0 resident

    int cur = 0;
    for (int c = 0; c < 4; ++c) {
        if (c < 3) stage(cur ^ 1, c + 1);   // prefetch next chunk

        for (int cg = 0; cg < 4; ++cg) {    // 4 sub-its of 32 cols
            const int c0 = cs * 512 + c * 128 + cg * 32;
            const __bf16* ab = &abuf[cur][cg * 16 * 512 + lane * 8];

            f32x16 acc0, acc1;
#pragma unroll
            for (int g = 0; g < 16; ++g) { acc0[g] = 0.f; acc1[g] = 0.f; }

            bf16x8 a[8];
            // K-half 0 (ks 0..7)
#pragma unroll
            for (int ks = 0; ks < 8; ++ks)
                a[ks] = *reinterpret_cast<const bf16x8*>(ab + ks * 512);
#pragma unroll
            for (int ks = 0; ks < 8; ++ks) {
                acc0 = __builtin_amdgcn_mfma_f32_32x32x16_bf16(a[ks], bfrag[0][ks], acc0, 0, 0, 0);
                acc1 = __builtin_amdgcn_mfma_f32_32x32x16_bf16(a[ks], bfrag[1][ks], acc1, 0, 0, 0);
            }
            // K-half 1 (ks 8..15)
#pragma unroll
            for (int ks = 0; ks < 8; ++ks)
                a[ks] = *reinterpret_cast<const bf16x8*>(ab + (8 + ks) * 512);
#pragma unroll
            for (int ks = 0; ks < 8; ++ks) {
                acc0 = __builtin_amdgcn_mfma_f32_32x32x16_bf16(a[ks], bfrag[0][8 + ks], acc0, 0, 0, 0);
                acc1 = __builtin_amdgcn_mfma_f32_32x32x16_bf16(a[ks], bfrag[1][8 + ks], acc1, 0, 0, 0);
            }

            // drain: entry at reg g = scaled_sim[row = wr0 + t*32 + cl31]
            //                                   [col = c0 + (g&3)+8*(g>>2)+4*half]
            const bool special = (c0 < wr0 + 64 && c0 + 32 > wr0) ||
                                 (c0 < p0 + 64 && c0 + 32 > p0);
            if (!special) {
#pragma unroll
                for (int g = 0; g < 16; ++g) {
                    sums0[g] += fast_exp2(acc0[g]);
                    sums1[g] += fast_exp2(acc1[g]);
                }
            } else {
                const int r0 = wr0 + cl31;        // acc0 rows
                const int r1 = wr0 + 32 + cl31;   // acc1 rows
#pragma unroll
                for (int g = 0; g < 16; ++g) {
                    const int col = c0 + (g & 3) + 8 * (g >> 2) + 4 * half;
                    {
                        const float e = fast_exp2(acc0[g]);
                        sums0[g] += (col == r0) ? 0.f : e;               // self-diag mask
                        if (col == (r0 ^ N_HALF)) pos_acc += acc0[g];    // positive
                    }
                    {
                        const float e = fast_exp2(acc1[g]);
                        sums1[g] += (col == r1) ? 0.f : e;
                        if (col == (r1 ^ N_HALF)) pos_acc += acc1[g];
                    }
                }
            }
        }

        // next chunk's stage was issued a full chunk ago -> drain is ~free.
        asm volatile("s_waitcnt vmcnt(0)" ::: "memory");
        __syncthreads();
        cur ^= 1;
    }

    // Epilogue: each lane's sums belong to one row; halves hold complementary
    // col-offset sets -> combine with one shfl_xor(32), store coalesced.
    {
        float s0 = 0.f, s1 = 0.f;
#pragma unroll
        for (int g = 0; g < 16; ++g) { s0 += sums0[g]; s1 += sums1[g]; }
        s0 += __shfl_xor(s0, 32, 64);
        s1 += __shfl_xor(s1, 32, 64);
        if (lane < 32) {
            rowsum_part[(size_t)cs * TWO_N + wr0 + cl31]      = s0;
            rowsum_part[(size_t)cs * TWO_N + wr0 + 32 + cl31] = s1;
        }
    }

    // Positive partial: every wave writes its slot (0 if no partner overlap).
#pragma unroll
    for (int m = 1; m < 64; m <<= 1) pos_acc += __shfl_xor(pos_acc, m, 64);
    if (lane == 0) pos_part[blockIdx.x * 8 + wave] = pos_acc;
}

// ---------------------------------------------------------------------------
// Kernel 3: per-row ln(sum of 16 partials), minus ln2 * positive partials
// (2048 pos slots; slot->row mapping irrelevant for the global sum).
// 8 blocks x 1024 threads, coalesced reads.
// ---------------------------------------------------------------------------
__global__ __launch_bounds__(1024) void fin1_kernel(const float* __restrict__ rowsum_part,
                                                    const float* __restrict__ pos_part,
                                                    float* __restrict__ block_part)
{
    __shared__ float red[16];
    const int t = threadIdx.x;
    const int r = blockIdx.x * 1024 + t;
    float acc = 0.f;
#pragma unroll
    for (int cs = 0; cs < 16; ++cs)
        acc += rowsum_part[(size_t)cs * TWO_N + r];
    float v = logf(acc);
    if (r < 2048)
        v -= 0.69314718055994531f * pos_part[r];
#pragma unroll
    for (int m = 1; m < 64; m <<= 1) v += __shfl_xor(v, m, 64);
    if ((t & 63) == 0) red[t >> 6] = v;
    __syncthreads();
    if (t == 0) {
        float s = 0.f;
#pragma unroll
        for (int w = 0; w < 16; ++w) s += red[w];
        block_part[blockIdx.x] = s;
    }
}

// ---------------------------------------------------------------------------
// Kernel 4: final scalar.
// ---------------------------------------------------------------------------
__global__ void fin2_kernel(const float* __restrict__ block_part, float* __restrict__ out)
{
    if (threadIdx.x == 0) {
        float s = 0.f;
#pragma unroll
        for (int i = 0; i < 8; ++i) s += block_part[i];
        out[0] = s / (float)TWO_N;
    }
}

// ---------------------------------------------------------------------------
extern "C" void kernel_launch(void* const* d_in, const int* in_sizes, int n_in,
                              void* d_out, int out_size, void* d_ws, size_t ws_size,
                              hipStream_t stream)
{
    const float* zis = (const float*)d_in[0];
    const float* zjs = (const float*)d_in[1];

    // ws: [0,4MB) swizzled bf16; then rowsum partials [16][8192] f32 (512KB);
    //     then pos partials [2048]; then block partials [8].
    unsigned short* swz = (unsigned short*)d_ws;
    float* rowsum_part  = (float*)((char*)d_ws + (size_t)TWO_N * DIMS * sizeof(unsigned short));
    float* pos_part     = rowsum_part + (size_t)16 * TWO_N;
    float* block_part   = pos_part + 2048;

    nrm_kernel<<<TWO_N / 8, 256, 0, stream>>>(zis, zjs, swz);
    ntx_kernel<<<256, 512, 0, stream>>>((const __bf16*)swz, rowsum_part, pos_part);
    fin1_kernel<<<8, 1024, 0, stream>>>(rowsum_part, pos_part, block_part);
    fin2_kernel<<<1, 64, 0, stream>>>(block_part, (float*)d_out);
}

// Round 12
// 95.685 us; speedup vs baseline: 3.7460x; 3.7460x over previous
//
#include <hip/hip_runtime.h>
#include <hip/hip_bf16.h>

#define TWO_N  8192
#define N_HALF 4096
#define DIMS   256

typedef __bf16 bf16x8 __attribute__((ext_vector_type(8)));
typedef float  f32x16 __attribute__((ext_vector_type(16)));
typedef unsigned short ushort8v __attribute__((ext_vector_type(8)));

// raw v_exp_f32 (args here are bounded |x| <= ~3, no denormal/range handling needed)
__device__ __forceinline__ float fast_exp2(float x) {
#if __has_builtin(__builtin_amdgcn_exp2f)
    return __builtin_amdgcn_exp2f(x);
#else
    float r; asm("v_exp_f32 %0, %1" : "=v"(r) : "v"(x)); return r;
#endif
}

// async global->LDS, 16B per lane: LDS dest = wave-uniform base (HW adds
// lane*16), global src = per-lane pointer (guide §5; m97 pattern).
#define GLOAD_LDS16(g, l)                                                      \
    __builtin_amdgcn_global_load_lds(                                          \
        (const __attribute__((address_space(1))) unsigned int*)(g),            \
        (__attribute__((address_space(3))) unsigned int*)(l), 16, 0, 0)

// ---------------------------------------------------------------------------
// Kernel 1: normalize rows of reps = cat([zjs, zis]), pre-scale by
// sqrt(2*log2(e)) so MFMA dot = (1/TEMP)*log2(e)*sim, and store in
// 32x32x16-MFMA fragment order: chunk = (row/32)*16 + kk  (kk = K/16 step),
// within chunk lane L = khalf*32 + (row%32) holds 8 bf16 of
// k = kk*16 + khalf*8 + j.  One 32-lane half-wave per row.
// ---------------------------------------------------------------------------
__global__ __launch_bounds__(256) void nrm_kernel(const float* __restrict__ zis,
                                                  const float* __restrict__ zjs,
                                                  unsigned short* __restrict__ swz)
{
    const int tid = threadIdx.x;
    const int l32 = tid & 31;
    const int row = blockIdx.x * 8 + (tid >> 5);
    const int k0  = l32 * 8;

    const float* src = (row < N_HALF) ? (zjs + (size_t)row * DIMS)
                                      : (zis + (size_t)(row - N_HALF) * DIMS);
    const float4 v0 = reinterpret_cast<const float4*>(src + k0)[0];
    const float4 v1 = reinterpret_cast<const float4*>(src + k0 + 4)[0];
    float ss = v0.x * v0.x + v0.y * v0.y + v0.z * v0.z + v0.w * v0.w
             + v1.x * v1.x + v1.y * v1.y + v1.z * v1.z + v1.w * v1.w;
#pragma unroll
    for (int m = 1; m < 32; m <<= 1) ss += __shfl_xor(ss, m, 64);
    // norms ~16 for N(0,1) rows; cosine eps path can never trigger
    const float inv = rsqrtf(ss) * 1.69864360045f;  // * sqrt(2*log2(e))

    const float vals[8] = {v0.x, v0.y, v0.z, v0.w, v1.x, v1.y, v1.z, v1.w};
    ushort8v o;
#pragma unroll
    for (int j = 0; j < 8; ++j) {
        __hip_bfloat16 b = __float2bfloat16(vals[j] * inv);
        o[j] = *reinterpret_cast<unsigned short*>(&b);
    }
    // kk = k0>>4 = l32>>1, khalf = l32&1
    const size_t addr = ((size_t)((row >> 5) * 16 + (l32 >> 1)) * 64
                         + (l32 & 1) * 32 + (row & 31)) * 8;
    *reinterpret_cast<ushort8v*>(swz + addr) = o;
}

// ---------------------------------------------------------------------------
// Kernel 2 (R11 layout — verified absmax 0.0 — with the spill fixed):
// 512x512 tile, 1 block/CU (grid 256), 8 waves x 64 rows, chunked LDS A
// (4 x 64KB dbuf), one vmcnt(0)+barrier per 128-col chunk, 32x32x16 MFMA.
// R11 failed on REGISTER SPILL, not the theory: VGPR_Count=128 (allocator
// constrained by __launch_bounds__(512,2)) vs ~240 live -> 295 MB scratch
// writes/dispatch. Fix: (1) sums0[16]/sums1[16] -> 2 scalars (all 16 C-regs
// of an acc belong to ONE sim-row under the verified mapping; arrays were
// pure waste, -30 VGPR); (2) __launch_bounds__(512) -- a 512-thread block
// intrinsically caps at 256 VGPR (2 waves/SIMD resident), LDS already limits
// to 1 block/CU, so no forced 128 cap. Est. ~210 VGPR -> no spill.
// D-mapping (R11-verified): reg g of acc_t = sim[row = wr0 + t*32 + (lane&31)]
//                                          [col = c0 + (g&3)+8*(g>>2)+4*(lane>>5)].
// ---------------------------------------------------------------------------
__global__ __launch_bounds__(512) void ntx_kernel(const __bf16* __restrict__ swz,
                                                  float* __restrict__ rowsum_part,
                                                  float* __restrict__ pos_part)
{
    __shared__ __bf16 abuf[2][32768];   // 2 x 64 KB (chunk double-buffer)

    const int lane = threadIdx.x & 63;
    const int wave = threadIdx.x >> 6;   // 0..7
    const int half = lane >> 5;          // k-half of A/B frags, col-offset group of C
    const int cl31 = lane & 31;          // C/D row within the 32-row group

    const int rg   = blockIdx.x & 15;    // 16 row groups of 512
    const int cs   = blockIdx.x >> 4;    // 16 col groups of 512
    const int wr0  = rg * 512 + wave * 64;
    const int p0   = wr0 ^ N_HALF;       // partner-row window (positives)
    const int g0   = wr0 >> 5;           // first 32-row fragment group

    // stage chunk c (128 cols = 4 col-32-groups x 16 K-chunks = 64 x 1KB):
    // wave w covers sub-chunks [w*8, w*8+8).
    auto stage = [&](int buf, int c) {
        const __bf16* gsrc = swz + ((size_t)(cs * 256 + c * 64 + wave * 8)) * 512 + lane * 8;
#pragma unroll
        for (int h = 0; h < 8; ++h)
            GLOAD_LDS16(gsrc + h * 512, &abuf[buf][(wave * 8 + h) * 512]);
    };

    stage(0, 0);   // chunk 0 in flight while B fragments load

    // Hoist B (row) fragments: 2 groups of 32 rows, 16 K-chunks each (128 VGPR).
    bf16x8 bfrag[2][16];
#pragma unroll
    for (int t = 0; t < 2; ++t)
#pragma unroll
        for (int ks = 0; ks < 16; ++ks)
            bfrag[t][ks] = *reinterpret_cast<const bf16x8*>(
                swz + (size_t)((g0 + t) * 16 + ks) * 512 + lane * 8);

    float s0 = 0.f, s1 = 0.f;   // per-lane row exp-sums (rows wr0+cl31, wr0+32+cl31)
    float pos_acc = 0.f;

    asm volatile("s_waitcnt vmcnt(0)" ::: "memory");
    __syncthreads();   // chunk 0 resident

    int cur = 0;
    for (int c = 0; c < 4; ++c) {
        if (c < 3) stage(cur ^ 1, c + 1);   // prefetch next chunk

        for (int cg = 0; cg < 4; ++cg) {    // 4 sub-its of 32 cols
            const int c0 = cs * 512 + c * 128 + cg * 32;
            const __bf16* ab = &abuf[cur][cg * 16 * 512 + lane * 8];

            f32x16 acc0, acc1;
#pragma unroll
            for (int g = 0; g < 16; ++g) { acc0[g] = 0.f; acc1[g] = 0.f; }

            bf16x8 a[8];
            // K-half 0 (ks 0..7)
#pragma unroll
            for (int ks = 0; ks < 8; ++ks)
                a[ks] = *reinterpret_cast<const bf16x8*>(ab + ks * 512);
#pragma unroll
            for (int ks = 0; ks < 8; ++ks) {
                acc0 = __builtin_amdgcn_mfma_f32_32x32x16_bf16(a[ks], bfrag[0][ks], acc0, 0, 0, 0);
                acc1 = __builtin_amdgcn_mfma_f32_32x32x16_bf16(a[ks], bfrag[1][ks], acc1, 0, 0, 0);
            }
            // K-half 1 (ks 8..15)
#pragma unroll
            for (int ks = 0; ks < 8; ++ks)
                a[ks] = *reinterpret_cast<const bf16x8*>(ab + (8 + ks) * 512);
#pragma unroll
            for (int ks = 0; ks < 8; ++ks) {
                acc0 = __builtin_amdgcn_mfma_f32_32x32x16_bf16(a[ks], bfrag[0][8 + ks], acc0, 0, 0, 0);
                acc1 = __builtin_amdgcn_mfma_f32_32x32x16_bf16(a[ks], bfrag[1][8 + ks], acc1, 0, 0, 0);
            }

            // drain (R11-verified mapping)
            const bool special = (c0 < wr0 + 64 && c0 + 32 > wr0) ||
                                 (c0 < p0 + 64 && c0 + 32 > p0);
            if (!special) {
#pragma unroll
                for (int g = 0; g < 16; ++g) {
                    s0 += fast_exp2(acc0[g]);
                    s1 += fast_exp2(acc1[g]);
                }
            } else {
                const int r0 = wr0 + cl31;        // acc0 rows
                const int r1 = wr0 + 32 + cl31;   // acc1 rows
#pragma unroll
                for (int g = 0; g < 16; ++g) {
                    const int col = c0 + (g & 3) + 8 * (g >> 2) + 4 * half;
                    {
                        const float e = fast_exp2(acc0[g]);
                        s0 += (col == r0) ? 0.f : e;                     // self-diag mask
                        if (col == (r0 ^ N_HALF)) pos_acc += acc0[g];    // positive
                    }
                    {
                        const float e = fast_exp2(acc1[g]);
                        s1 += (col == r1) ? 0.f : e;
                        if (col == (r1 ^ N_HALF)) pos_acc += acc1[g];
                    }
                }
            }
        }

        // next chunk's stage was issued a full chunk ago -> drain is ~free.
        asm volatile("s_waitcnt vmcnt(0)" ::: "memory");
        __syncthreads();
        cur ^= 1;
    }

    // Epilogue: halves hold complementary col-offset sets of the same row ->
    // combine with one shfl_xor(32), store coalesced.
    s0 += __shfl_xor(s0, 32, 64);
    s1 += __shfl_xor(s1, 32, 64);
    if (lane < 32) {
        rowsum_part[(size_t)cs * TWO_N + wr0 + cl31]      = s0;
        rowsum_part[(size_t)cs * TWO_N + wr0 + 32 + cl31] = s1;
    }

    // Positive partial: every wave writes its slot (0 if no partner overlap).
#pragma unroll
    for (int m = 1; m < 64; m <<= 1) pos_acc += __shfl_xor(pos_acc, m, 64);
    if (lane == 0) pos_part[blockIdx.x * 8 + wave] = pos_acc;
}

// ---------------------------------------------------------------------------
// Kernel 3: per-row ln(sum of 16 partials), minus ln2 * positive partials
// (2048 pos slots; slot->row mapping irrelevant for the global sum).
// 8 blocks x 1024 threads, coalesced reads.
// ---------------------------------------------------------------------------
__global__ __launch_bounds__(1024) void fin1_kernel(const float* __restrict__ rowsum_part,
                                                    const float* __restrict__ pos_part,
                                                    float* __restrict__ block_part)
{
    __shared__ float red[16];
    const int t = threadIdx.x;
    const int r = blockIdx.x * 1024 + t;
    float acc = 0.f;
#pragma unroll
    for (int cs = 0; cs < 16; ++cs)
        acc += rowsum_part[(size_t)cs * TWO_N + r];
    float v = logf(acc);
    if (r < 2048)
        v -= 0.69314718055994531f * pos_part[r];
#pragma unroll
    for (int m = 1; m < 64; m <<= 1) v += __shfl_xor(v, m, 64);
    if ((t & 63) == 0) red[t >> 6] = v;
    __syncthreads();
    if (t == 0) {
        float s = 0.f;
#pragma unroll
        for (int w = 0; w < 16; ++w) s += red[w];
        block_part[blockIdx.x] = s;
    }
}

// ---------------------------------------------------------------------------
// Kernel 4: final scalar.
// ---------------------------------------------------------------------------
__global__ void fin2_kernel(const float* __restrict__ block_part, float* __restrict__ out)
{
    if (threadIdx.x == 0) {
        float s = 0.f;
#pragma unroll
        for (int i = 0; i < 8; ++i) s += block_part[i];
        out[0] = s / (float)TWO_N;
    }
}

// ---------------------------------------------------------------------------
extern "C" void kernel_launch(void* const* d_in, const int* in_sizes, int n_in,
                              void* d_out, int out_size, void* d_ws, size_t ws_size,
                              hipStream_t stream)
{
    const float* zis = (const float*)d_in[0];
    const float* zjs = (const float*)d_in[1];

    // ws: [0,4MB) swizzled bf16; then rowsum partials [16][8192] f32 (512KB);
    //     then pos partials [2048]; then block partials [8].
    unsigned short* swz = (unsigned short*)d_ws;
    float* rowsum_part  = (float*)((char*)d_ws + (size_t)TWO_N * DIMS * sizeof(unsigned short));
    float* pos_part     = rowsum_part + (size_t)16 * TWO_N;
    float* block_part   = pos_part + 2048;

    nrm_kernel<<<TWO_N / 8, 256, 0, stream>>>(zis, zjs, swz);
    ntx_kernel<<<256, 512, 0, stream>>>((const __bf16*)swz, rowsum_part, pos_part);
    fin1_kernel<<<8, 1024, 0, stream>>>(rowsum_part, pos_part, block_part);
    fin2_kernel<<<1, 64, 0, stream>>>(block_part, (float*)d_out);
}

// Round 13
// 95.476 us; speedup vs baseline: 3.7542x; 1.0022x over previous
//
#include <hip/hip_runtime.h>
#include <hip/hip_bf16.h>

#define TWO_N  8192
#define N_HALF 4096
#define DIMS   256

typedef __bf16 bf16x8 __attribute__((ext_vector_type(8)));
typedef float  f32x4  __attribute__((ext_vector_type(4)));
typedef unsigned short ushort8v __attribute__((ext_vector_type(8)));

// raw v_exp_f32 (args here are bounded |x| <= ~3, no denormal/range handling needed)
__device__ __forceinline__ float fast_exp2(float x) {
#if __has_builtin(__builtin_amdgcn_exp2f)
    return __builtin_amdgcn_exp2f(x);
#else
    float r; asm("v_exp_f32 %0, %1" : "=v"(r) : "v"(x)); return r;
#endif
}

// async global->LDS, 16B per lane: LDS dest = wave-uniform base (HW adds
// lane*16), global src = per-lane pointer (guide §5; m97 pattern).
#define GLOAD_LDS16(g, l)                                                      \
    __builtin_amdgcn_global_load_lds(                                          \
        (const __attribute__((address_space(1))) unsigned int*)(g),            \
        (__attribute__((address_space(3))) unsigned int*)(l), 16, 0, 0)

// ---------------------------------------------------------------------------
// Kernel 1: normalize rows of reps = cat([zjs, zis]), pre-scale by
// sqrt(2*log2(e)) so MFMA dot = (1/TEMP)*log2(e)*sim, and store in MFMA
// fragment-swizzled order: chunk = ((row/16)*8 + kk)*64 + quad*16 + (row%16),
// each chunk = 8 bf16 = elements k in [quad*8 + kk*32, +8) of that row.
// One 32-lane half-wave per row (8 rows / 256-thread block).
// ---------------------------------------------------------------------------
__global__ __launch_bounds__(256) void nrm_kernel(const float* __restrict__ zis,
                                                  const float* __restrict__ zjs,
                                                  unsigned short* __restrict__ swz)
{
    const int tid = threadIdx.x;
    const int l32 = tid & 31;
    const int row = blockIdx.x * 8 + (tid >> 5);
    const int k0  = l32 * 8;

    const float* src = (row < N_HALF) ? (zjs + (size_t)row * DIMS)
                                      : (zis + (size_t)(row - N_HALF) * DIMS);
    const float4 v0 = reinterpret_cast<const float4*>(src + k0)[0];
    const float4 v1 = reinterpret_cast<const float4*>(src + k0 + 4)[0];
    float ss = v0.x * v0.x + v0.y * v0.y + v0.z * v0.z + v0.w * v0.w
             + v1.x * v1.x + v1.y * v1.y + v1.z * v1.z + v1.w * v1.w;
#pragma unroll
    for (int m = 1; m < 32; m <<= 1) ss += __shfl_xor(ss, m, 64);
    // norms ~16 for N(0,1) rows; cosine eps path can never trigger
    const float inv = rsqrtf(ss) * 1.69864360045f;  // * sqrt(2*log2(e))

    const float vals[8] = {v0.x, v0.y, v0.z, v0.w, v1.x, v1.y, v1.z, v1.w};
    ushort8v o;
#pragma unroll
    for (int j = 0; j < 8; ++j) {
        __hip_bfloat16 b = __float2bfloat16(vals[j] * inv);
        o[j] = *reinterpret_cast<unsigned short*>(&b);
    }
    // kk = k0>>5 = l32>>2, quad = l32&3
    const int chunk = ((row >> 4) * 8 + (l32 >> 2)) * 64 + (l32 & 3) * 16 + (row & 15);
    *reinterpret_cast<ushort8v*>(swz + (size_t)chunk * 8) = o;
}

// ---------------------------------------------------------------------------
// Kernel 2 (R8 base + paired 8-chain MFMA bursts): 512x512 tile, 1 block/CU
// (grid 256), 8 waves, chunked LDS A (4 x 64KB dbuf), one vmcnt(0)+barrier
// per 128-col chunk, 16x16x32 MFMA.
// CHANGE vs R8 (91.9us best): sub-its processed in PAIRS with the two
// 32-MFMA bursts INTERLEAVED kk-wise -> 8 independent accumulation chains
// per wave (was 4). R8/R9/R12 exonerated traffic, occupancy, drain
// correlation, and shape; the remaining suspect is MFMA dependent-chain
// latency (4 chains x ~19.4cyc/SIMD = 78cyc tolerance, likely < real
// latency -> inter-kk stalls). 8 chains tolerate ~155cyc. Next pair's
// ds_reads issue right after the fused burst, before the two drains.
// Per-row drain order unchanged -> bit-identical row sums.
// ---------------------------------------------------------------------------
__global__ __launch_bounds__(512) void ntx_kernel(const __bf16* __restrict__ swz,
                                                  float* __restrict__ rowsum_part,
                                                  float* __restrict__ pos_part)
{
    __shared__ __bf16 abuf[2][32768];   // 2 x 64 KB (chunk double-buffer)

    const int lane = threadIdx.x & 63;
    const int wave = threadIdx.x >> 6;   // 0..7
    const int l15  = lane & 15;
    const int quad = lane >> 4;

    const int rg   = blockIdx.x & 15;    // 16 row groups of 512
    const int cs   = blockIdx.x >> 4;    // 16 col groups of 512
    const int wr0  = rg * 512 + wave * 64;
    const int p0   = wr0 ^ N_HALF;       // partner-row window (positives)

    // stage chunk c (128 cols = 8 col-16-groups) into abuf[buf]:
    // wave w covers group w (4096 elems = 8 KB) as 8 x 1KB wave-issues.
    auto stage = [&](int buf, int c) {
        const __bf16* gsrc = swz + (size_t)(cs * 32 + c * 8 + wave) * 4096 + lane * 8;
#pragma unroll
        for (int h = 0; h < 8; ++h)
            GLOAD_LDS16(gsrc + h * 512, &abuf[buf][wave * 4096 + h * 512]);
    };

    stage(0, 0);   // chunk 0 in flight while B fragments load

    // Hoist B (row) fragments: 4 groups of 16 rows, 8 K-chunks each (128 VGPR).
    bf16x8 bfrag[4][8];
#pragma unroll
    for (int t = 0; t < 4; ++t) {
        const __bf16* bp = swz + (size_t)((wr0 >> 4) + t) * 4096 + lane * 8;
#pragma unroll
        for (int kk = 0; kk < 8; ++kk)
            bfrag[t][kk] = *reinterpret_cast<const bf16x8*>(bp + kk * 512);
    }

    float sum_exp[4] = {0.f, 0.f, 0.f, 0.f};
    float pos_acc = 0.f;

    // exp2 + row-sum + diag/positive handling for a completed acc set.
    auto drain = [&](const f32x4* acc, int c0) {
        const bool special = (c0 < wr0 + 64 && c0 + 16 > wr0) ||
                             (c0 < p0 + 64 && c0 + 16 > p0);
        if (!special) {
#pragma unroll
            for (int t = 0; t < 4; ++t)
#pragma unroll
                for (int j = 0; j < 4; ++j)
                    sum_exp[t] += fast_exp2(acc[t][j]);
        } else {
#pragma unroll
            for (int t = 0; t < 4; ++t) {
                const int r = wr0 + t * 16 + l15;
#pragma unroll
                for (int j = 0; j < 4; ++j) {
                    const int col = c0 + quad * 4 + j;
                    const float e = fast_exp2(acc[t][j]);
                    sum_exp[t] += (col == r) ? 0.f : e;               // self-diag mask
                    if (col == (r ^ N_HALF)) pos_acc += acc[t][j];    // positive
                }
            }
        }
    };

    asm volatile("s_waitcnt vmcnt(0)" ::: "memory");
    __syncthreads();   // chunk 0 resident

    int cur = 0;
    for (int c = 0; c < 4; ++c) {
        if (c < 3) stage(cur ^ 1, c + 1);   // prefetch next chunk

        const int cc_base = cs * 512 + c * 128;

        // load first sub-it pair of the chunk
        bf16x8 a0[8], a1[8];
#pragma unroll
        for (int kk = 0; kk < 8; ++kk) {
            a0[kk] = *reinterpret_cast<const bf16x8*>(&abuf[cur][kk * 512 + lane * 8]);
            a1[kk] = *reinterpret_cast<const bf16x8*>(&abuf[cur][4096 + kk * 512 + lane * 8]);
        }

        for (int p = 0; p < 4; ++p) {       // 4 pairs of 16-col sub-its
            const int it = p * 2;

            // fused 64-MFMA burst, kk-interleaved: 8 independent chains.
            f32x4 accE[4] = {{0.f,0.f,0.f,0.f},{0.f,0.f,0.f,0.f},
                             {0.f,0.f,0.f,0.f},{0.f,0.f,0.f,0.f}};
            f32x4 accO[4] = {{0.f,0.f,0.f,0.f},{0.f,0.f,0.f,0.f},
                             {0.f,0.f,0.f,0.f},{0.f,0.f,0.f,0.f}};
#pragma unroll
            for (int kk = 0; kk < 8; ++kk) {
#pragma unroll
                for (int t = 0; t < 4; ++t)
                    accE[t] = __builtin_amdgcn_mfma_f32_16x16x32_bf16(
                        a0[kk], bfrag[t][kk], accE[t], 0, 0, 0);
#pragma unroll
                for (int t = 0; t < 4; ++t)
                    accO[t] = __builtin_amdgcn_mfma_f32_16x16x32_bf16(
                        a1[kk], bfrag[t][kk], accO[t], 0, 0, 0);
            }

            // next pair's LDS reads issue under the in-flight MFMAs.
            if (p < 3) {
#pragma unroll
                for (int kk = 0; kk < 8; ++kk) {
                    a0[kk] = *reinterpret_cast<const bf16x8*>(
                        &abuf[cur][(it + 2) * 4096 + kk * 512 + lane * 8]);
                    a1[kk] = *reinterpret_cast<const bf16x8*>(
                        &abuf[cur][(it + 3) * 4096 + kk * 512 + lane * 8]);
                }
            }

            drain(accE, cc_base + it * 16);
            drain(accO, cc_base + (it + 1) * 16);
        }

        // next chunk's stage was issued a full chunk ago -> drain is ~free.
        asm volatile("s_waitcnt vmcnt(0)" ::: "memory");
        __syncthreads();
        cur ^= 1;
    }

    // Per-row partial: reduce over the 4 quads (col groups), one store per row.
#pragma unroll
    for (int t = 0; t < 4; ++t) {
        float s = sum_exp[t];
        s += __shfl_xor(s, 16, 64);
        s += __shfl_xor(s, 32, 64);
        if (lane < 16)
            rowsum_part[(size_t)cs * TWO_N + wr0 + t * 16 + lane] = s;
    }

    // Positive partial: every wave writes its slot (0 if no partner overlap).
#pragma unroll
    for (int m = 1; m < 64; m <<= 1) pos_acc += __shfl_xor(pos_acc, m, 64);
    if (lane == 0) pos_part[blockIdx.x * 8 + wave] = pos_acc;
}

// ---------------------------------------------------------------------------
// Kernel 3: per-row ln(sum of 16 partials), minus ln2 * positive partials
// (2048 pos slots; slot->row mapping irrelevant for the global sum).
// 8 blocks x 1024 threads, coalesced reads.
// ---------------------------------------------------------------------------
__global__ __launch_bounds__(1024) void fin1_kernel(const float* __restrict__ rowsum_part,
                                                    const float* __restrict__ pos_part,
                                                    float* __restrict__ block_part)
{
    __shared__ float red[16];
    const int t = threadIdx.x;
    const int r = blockIdx.x * 1024 + t;
    float acc = 0.f;
#pragma unroll
    for (int cs = 0; cs < 16; ++cs)
        acc += rowsum_part[(size_t)cs * TWO_N + r];
    float v = logf(acc);
    if (r < 2048)
        v -= 0.69314718055994531f * pos_part[r];
#pragma unroll
    for (int m = 1; m < 64; m <<= 1) v += __shfl_xor(v, m, 64);
    if ((t & 63) == 0) red[t >> 6] = v;
    __syncthreads();
    if (t == 0) {
        float s = 0.f;
#pragma unroll
        for (int w = 0; w < 16; ++w) s += red[w];
        block_part[blockIdx.x] = s;
    }
}

// ---------------------------------------------------------------------------
// Kernel 4: final scalar.
// ---------------------------------------------------------------------------
__global__ void fin2_kernel(const float* __restrict__ block_part, float* __restrict__ out)
{
    if (threadIdx.x == 0) {
        float s = 0.f;
#pragma unroll
        for (int i = 0; i < 8; ++i) s += block_part[i];
        out[0] = s / (float)TWO_N;
    }
}

// ---------------------------------------------------------------------------
extern "C" void kernel_launch(void* const* d_in, const int* in_sizes, int n_in,
                              void* d_out, int out_size, void* d_ws, size_t ws_size,
                              hipStream_t stream)
{
    const float* zis = (const float*)d_in[0];
    const float* zjs = (const float*)d_in[1];

    // ws: [0,4MB) swizzled bf16; then rowsum partials [16][8192] f32 (512KB);
    //     then pos partials [2048]; then block partials [8].
    unsigned short* swz = (unsigned short*)d_ws;
    float* rowsum_part  = (float*)((char*)d_ws + (size_t)TWO_N * DIMS * sizeof(unsigned short));
    float* pos_part     = rowsum_part + (size_t)16 * TWO_N;
    float* block_part   = pos_part + 2048;

    nrm_kernel<<<TWO_N / 8, 256, 0, stream>>>(zis, zjs, swz);
    ntx_kernel<<<256, 512, 0, stream>>>((const __bf16*)swz, rowsum_part, pos_part);
    fin1_kernel<<<8, 1024, 0, stream>>>(rowsum_part, pos_part, block_part);
    fin2_kernel<<<1, 64, 0, stream>>>(block_part, (float*)d_out);
}

// Round 14
// 93.100 us; speedup vs baseline: 3.8500x; 1.0255x over previous
//
#include <hip/hip_runtime.h>
#include <hip/hip_bf16.h>

#define TWO_N  8192
#define N_HALF 4096
#define DIMS   256

typedef __bf16 bf16x8 __attribute__((ext_vector_type(8)));
typedef float  f32x4  __attribute__((ext_vector_type(4)));
typedef unsigned short ushort8v __attribute__((ext_vector_type(8)));

// raw v_exp_f32 (args here are bounded |x| <= ~3, no denormal/range handling needed)
__device__ __forceinline__ float fast_exp2(float x) {
#if __has_builtin(__builtin_amdgcn_exp2f)
    return __builtin_amdgcn_exp2f(x);
#else
    float r; asm("v_exp_f32 %0, %1" : "=v"(r) : "v"(x)); return r;
#endif
}

// async global->LDS, 16B per lane: LDS dest = wave-uniform base (HW adds
// lane*16), global src = per-lane pointer (guide §5; m97 pattern).
#define GLOAD_LDS16(g, l)                                                      \
    __builtin_amdgcn_global_load_lds(                                          \
        (const __attribute__((address_space(1))) unsigned int*)(g),            \
        (__attribute__((address_space(3))) unsigned int*)(l), 16, 0, 0)

// ---------------------------------------------------------------------------
// Kernel 1: normalize rows of reps = cat([zjs, zis]), pre-scale by
// sqrt(2*log2(e)) so MFMA dot = (1/TEMP)*log2(e)*sim, and store in MFMA
// fragment-swizzled order: chunk = ((row/16)*8 + kk)*64 + quad*16 + (row%16),
// each chunk = 8 bf16 = elements k in [quad*8 + kk*32, +8) of that row.
// One 32-lane half-wave per row (8 rows / 256-thread block).
// ---------------------------------------------------------------------------
__global__ __launch_bounds__(256) void nrm_kernel(const float* __restrict__ zis,
                                                  const float* __restrict__ zjs,
                                                  unsigned short* __restrict__ swz)
{
    const int tid = threadIdx.x;
    const int l32 = tid & 31;
    const int row = blockIdx.x * 8 + (tid >> 5);
    const int k0  = l32 * 8;

    const float* src = (row < N_HALF) ? (zjs + (size_t)row * DIMS)
                                      : (zis + (size_t)(row - N_HALF) * DIMS);
    const float4 v0 = reinterpret_cast<const float4*>(src + k0)[0];
    const float4 v1 = reinterpret_cast<const float4*>(src + k0 + 4)[0];
    float ss = v0.x * v0.x + v0.y * v0.y + v0.z * v0.z + v0.w * v0.w
             + v1.x * v1.x + v1.y * v1.y + v1.z * v1.z + v1.w * v1.w;
#pragma unroll
    for (int m = 1; m < 32; m <<= 1) ss += __shfl_xor(ss, m, 64);
    // norms ~16 for N(0,1) rows; cosine eps path can never trigger
    const float inv = rsqrtf(ss) * 1.69864360045f;  // * sqrt(2*log2(e))

    const float vals[8] = {v0.x, v0.y, v0.z, v0.w, v1.x, v1.y, v1.z, v1.w};
    ushort8v o;
#pragma unroll
    for (int j = 0; j < 8; ++j) {
        __hip_bfloat16 b = __float2bfloat16(vals[j] * inv);
        o[j] = *reinterpret_cast<unsigned short*>(&b);
    }
    // kk = k0>>5 = l32>>2, quad = l32&3
    const int chunk = ((row >> 4) * 8 + (l32 >> 2)) * 64 + (l32 & 3) * 16 + (row & 15);
    *reinterpret_cast<ushort8v*>(swz + (size_t)chunk * 8) = o;
}

// ---------------------------------------------------------------------------
// Kernel 2 (cross-block async + LDS staging): 256x512 tile, 256-thr blocks
// (4 waves x 64 rows), 2 INDEPENDENT blocks/CU (grid 512 = 32 rg x 16 cs),
// chunked LDS A (8 chunks of 64 cols; 2 x 32KB dbuf = 64KB/block), one
// vmcnt(0)+barrier per chunk (~1200cyc), 16x16x32 MFMA, reg-dbuf a0/a1.
// WHY vs R8 (91.9 best): R8's single 512-thr lockstep block drains all 8
// waves at every chunk barrier -> CU idle; R0's two unsynced blocks/CU
// overlapped each other's stalls (m114) but paid 4x traffic. This combines
// them: same 8 waves/CU, same L2 traffic class as R8, but the two resident
// blocks' barriers are UNALIGNED -> one block computes through the other's
// drain. Also 256-thr blocks get the full 256-VGPR allocation (R0: ~230
// live, no spill) instead of the 128-cap hipcc applies to 512-thr blocks
// (R11/R13 counters: VGPR_Count=128 + scratch traffic).
// Math bit-identical to R8 (same fragments, same per-row drain order).
// ---------------------------------------------------------------------------
__global__ __launch_bounds__(256, 2) void ntx_kernel(const __bf16* __restrict__ swz,
                                                     float* __restrict__ rowsum_part,
                                                     float* __restrict__ pos_part)
{
    __shared__ __bf16 abuf[2][16384];   // 2 x 32 KB (64-col chunk dbuf)

    const int lane = threadIdx.x & 63;
    const int wave = threadIdx.x >> 6;   // 0..3
    const int l15  = lane & 15;
    const int quad = lane >> 4;

    const int rg   = blockIdx.x & 31;    // 32 row groups of 256
    const int cs   = blockIdx.x >> 5;    // 16 col groups of 512
    const int wr0  = rg * 256 + wave * 64;
    const int p0   = wr0 ^ N_HALF;       // partner-row window (positives)

    // stage chunk c (64 cols = 4 col-16-groups): wave w stages group w
    // (4096 elems = 8KB) as 8 x 1KB wave-issues.
    auto stage = [&](int buf, int c) {
        const __bf16* gsrc = swz + (size_t)(cs * 32 + c * 4 + wave) * 4096 + lane * 8;
#pragma unroll
        for (int h = 0; h < 8; ++h)
            GLOAD_LDS16(gsrc + h * 512, &abuf[buf][wave * 4096 + h * 512]);
    };

    stage(0, 0);   // chunk 0 in flight while B fragments load

    // Hoist B (row) fragments: 4 groups of 16 rows, 8 K-chunks each (128 VGPR).
    bf16x8 bfrag[4][8];
#pragma unroll
    for (int t = 0; t < 4; ++t) {
        const __bf16* bp = swz + (size_t)((wr0 >> 4) + t) * 4096 + lane * 8;
#pragma unroll
        for (int kk = 0; kk < 8; ++kk)
            bfrag[t][kk] = *reinterpret_cast<const bf16x8*>(bp + kk * 512);
    }

    float sum_exp[4] = {0.f, 0.f, 0.f, 0.f};
    float pos_acc = 0.f;

    // 32-MFMA burst + exp2/row-sum drain for one 16-col sub-it.
    auto compute = [&](const bf16x8* af, int c0) {
        f32x4 acc[4] = {{0.f, 0.f, 0.f, 0.f}, {0.f, 0.f, 0.f, 0.f},
                        {0.f, 0.f, 0.f, 0.f}, {0.f, 0.f, 0.f, 0.f}};
#pragma unroll
        for (int kk = 0; kk < 8; ++kk) {
#pragma unroll
            for (int t = 0; t < 4; ++t)
                acc[t] = __builtin_amdgcn_mfma_f32_16x16x32_bf16(
                    af[kk], bfrag[t][kk], acc[t], 0, 0, 0);
        }
        const bool special = (c0 < wr0 + 64 && c0 + 16 > wr0) ||
                             (c0 < p0 + 64 && c0 + 16 > p0);
        if (!special) {
#pragma unroll
            for (int t = 0; t < 4; ++t)
#pragma unroll
                for (int j = 0; j < 4; ++j)
                    sum_exp[t] += fast_exp2(acc[t][j]);
        } else {
#pragma unroll
            for (int t = 0; t < 4; ++t) {
                const int r = wr0 + t * 16 + l15;
#pragma unroll
                for (int j = 0; j < 4; ++j) {
                    const int col = c0 + quad * 4 + j;
                    const float e = fast_exp2(acc[t][j]);
                    sum_exp[t] += (col == r) ? 0.f : e;               // self-diag mask
                    if (col == (r ^ N_HALF)) pos_acc += acc[t][j];    // positive
                }
            }
        }
    };

    asm volatile("s_waitcnt vmcnt(0)" ::: "memory");
    __syncthreads();   // chunk 0 resident

    int cur = 0;
    for (int c = 0; c < 8; ++c) {
        if (c < 7) stage(cur ^ 1, c + 1);   // prefetch next chunk

        const int cc_base = cs * 512 + c * 64;

        // 4 sub-its (16 cols each) from LDS, register double-buffered.
        bf16x8 a0[8], a1[8];
#pragma unroll
        for (int kk = 0; kk < 8; ++kk)
            a0[kk] = *reinterpret_cast<const bf16x8*>(&abuf[cur][kk * 512 + lane * 8]);

        for (int it = 0; it < 4; it += 2) {
#pragma unroll
            for (int kk = 0; kk < 8; ++kk)
                a1[kk] = *reinterpret_cast<const bf16x8*>(
                    &abuf[cur][(it + 1) * 4096 + kk * 512 + lane * 8]);
            compute(a0, cc_base + it * 16);
            if (it + 2 < 4) {
#pragma unroll
                for (int kk = 0; kk < 8; ++kk)
                    a0[kk] = *reinterpret_cast<const bf16x8*>(
                        &abuf[cur][(it + 2) * 4096 + kk * 512 + lane * 8]);
            }
            compute(a1, cc_base + (it + 1) * 16);
        }

        // next chunk's stage was issued a full chunk ago -> drain is cheap,
        // and the partner block on this CU computes through our barrier.
        asm volatile("s_waitcnt vmcnt(0)" ::: "memory");
        __syncthreads();
        cur ^= 1;
    }

    // Per-row partial: reduce over the 4 quads (col groups), one store per row.
#pragma unroll
    for (int t = 0; t < 4; ++t) {
        float s = sum_exp[t];
        s += __shfl_xor(s, 16, 64);
        s += __shfl_xor(s, 32, 64);
        if (lane < 16)
            rowsum_part[(size_t)cs * TWO_N + wr0 + t * 16 + lane] = s;
    }

    // Positive partial: every wave writes its slot (0 if no partner overlap).
#pragma unroll
    for (int m = 1; m < 64; m <<= 1) pos_acc += __shfl_xor(pos_acc, m, 64);
    if (lane == 0) pos_part[blockIdx.x * 4 + wave] = pos_acc;
}

// ---------------------------------------------------------------------------
// Kernel 3: per-row ln(sum of 16 partials), minus ln2 * positive partials
// (2048 pos slots; slot->row mapping irrelevant for the global sum).
// 8 blocks x 1024 threads, coalesced reads.
// ---------------------------------------------------------------------------
__global__ __launch_bounds__(1024) void fin1_kernel(const float* __restrict__ rowsum_part,
                                                    const float* __restrict__ pos_part,
                                                    float* __restrict__ block_part)
{
    __shared__ float red[16];
    const int t = threadIdx.x;
    const int r = blockIdx.x * 1024 + t;
    float acc = 0.f;
#pragma unroll
    for (int cs = 0; cs < 16; ++cs)
        acc += rowsum_part[(size_t)cs * TWO_N + r];
    float v = logf(acc);
    if (r < 2048)
        v -= 0.69314718055994531f * pos_part[r];
#pragma unroll
    for (int m = 1; m < 64; m <<= 1) v += __shfl_xor(v, m, 64);
    if ((t & 63) == 0) red[t >> 6] = v;
    __syncthreads();
    if (t == 0) {
        float s = 0.f;
#pragma unroll
        for (int w = 0; w < 16; ++w) s += red[w];
        block_part[blockIdx.x] = s;
    }
}

// ---------------------------------------------------------------------------
// Kernel 4: final scalar.
// ---------------------------------------------------------------------------
__global__ void fin2_kernel(const float* __restrict__ block_part, float* __restrict__ out)
{
    if (threadIdx.x == 0) {
        float s = 0.f;
#pragma unroll
        for (int i = 0; i < 8; ++i) s += block_part[i];
        out[0] = s / (float)TWO_N;
    }
}

// ---------------------------------------------------------------------------
extern "C" void kernel_launch(void* const* d_in, const int* in_sizes, int n_in,
                              void* d_out, int out_size, void* d_ws, size_t ws_size,
                              hipStream_t stream)
{
    const float* zis = (const float*)d_in[0];
    const float* zjs = (const float*)d_in[1];

    // ws: [0,4MB) swizzled bf16; then rowsum partials [16][8192] f32 (512KB);
    //     then pos partials [2048]; then block partials [8].
    unsigned short* swz = (unsigned short*)d_ws;
    float* rowsum_part  = (float*)((char*)d_ws + (size_t)TWO_N * DIMS * sizeof(unsigned short));
    float* pos_part     = rowsum_part + (size_t)16 * TWO_N;
    float* block_part   = pos_part + 2048;

    nrm_kernel<<<TWO_N / 8, 256, 0, stream>>>(zis, zjs, swz);
    ntx_kernel<<<512, 256, 0, stream>>>((const __bf16*)swz, rowsum_part, pos_part);
    fin1_kernel<<<8, 1024, 0, stream>>>(rowsum_part, pos_part, block_part);
    fin2_kernel<<<1, 64, 0, stream>>>(block_part, (float*)d_out);
}